// Round 4
// baseline (334.774 us; speedup 1.0000x reference)
//
#include <hip/hip_runtime.h>
#include <hip/hip_bf16.h>
#include <stdint.h>

#define BATCH 4
#define SEQ 2048
#define DMODEL 512
#define NHEAD 8
#define HD 64

using f32x4 = __attribute__((ext_vector_type(4))) float;
using bfrag = __attribute__((ext_vector_type(8))) short;

__device__ __forceinline__ short f2bf(float f) {
  uint32_t x = __builtin_bit_cast(uint32_t, f);
  uint32_t r = (x + 0x7fffu + ((x >> 16) & 1u)) >> 16;
  return (short)r;
}
__device__ __forceinline__ float bf2f(short s) {
  return __builtin_bit_cast(float, ((uint32_t)(uint16_t)s) << 16);
}

// ---------------- dtype sniffer (proven: flags 1 => inputs are float32) ------
__global__ void sniff(const uint32_t* __restrict__ x, int* __restrict__ flag) {
  const int tid = threadIdx.x;
  bool bad = false;
#pragma unroll
  for (int i = 0; i < 8; ++i) {
    const uint32_t w = x[tid * 8 + i];
    const uint32_t elo = (w >> 7) & 0xffu;
    const uint32_t ehi = (w >> 23) & 0xffu;
    bad |= (elo >= 0xB0u) | (ehi >= 0xB0u);
  }
  const unsigned long long m = __ballot(bad);
  if (tid == 0) *flag = (m != 0ull) ? 1 : 0;
}

// ---------------- embeddings -> bf16 (f32 downconvert or bf16 copy) ----------
__global__ __launch_bounds__(256) void conv_x(const void* __restrict__ in,
                                              short* __restrict__ out,
                                              const int* __restrict__ flag) {
  const int i = (blockIdx.x * 256 + threadIdx.x) * 8;
  if (*flag) {
    const float* f = (const float*)in;
    short r[8];
#pragma unroll
    for (int j = 0; j < 8; ++j) r[j] = f2bf(f[i + j]);
    *(bfrag*)&out[i] = *(bfrag*)r;
  } else {
    *(bfrag*)&out[i] = *(const bfrag*)&((const short*)in)[i];
  }
}

// ---------------- weight transpose (+convert): Wt[n][k] = W[k][n] ------------
__global__ __launch_bounds__(256) void transpose_w(const void* __restrict__ in,
                                                   short* __restrict__ out,
                                                   const int* __restrict__ flag) {
  __shared__ short t[32][33];
  const int n0 = blockIdx.x * 32, k0 = blockIdx.y * 32;
  const int tx = threadIdx.x, ty = threadIdx.y;
  const bool isf32 = (*flag != 0);
#pragma unroll
  for (int i = ty; i < 32; i += 8) {
    const int idx = (k0 + i) * DMODEL + n0 + tx;
    t[i][tx] = isf32 ? f2bf(((const float*)in)[idx]) : ((const short*)in)[idx];
  }
  __syncthreads();
#pragma unroll
  for (int i = ty; i < 32; i += 8) out[(n0 + i) * DMODEL + k0 + tx] = t[tx][i];
}

// ---------------- QKV projection GEMM (bf16 MFMA) ----------------------------
// C(8192x512) = X @ W; Wt is W^T (N x K). grid.z selects q/k/v.
// Output written in (B, H, S, DH) bf16 layout.
__global__ __launch_bounds__(256) void gemm_qkv(const short* __restrict__ X,
                                                const short* __restrict__ WtAll,
                                                short* __restrict__ Qo,
                                                short* __restrict__ Ko,
                                                short* __restrict__ Vo) {
  __shared__ __align__(16) short As[64 * 40];
  __shared__ __align__(16) short Bs[64 * 40];
  const int which = blockIdx.z;
  const short* Wt = WtAll + which * DMODEL * DMODEL;
  const int m0 = blockIdx.y * 64, n0 = blockIdx.x * 64;
  const int tid = threadIdx.x, lane = tid & 63, wave = tid >> 6;
  const int srow = tid >> 2, sseg = tid & 3;
  f32x4 acc[4] = {};
  for (int kc = 0; kc < DMODEL; kc += 32) {
    *(bfrag*)&As[srow * 40 + sseg * 8] =
        *(const bfrag*)&X[(m0 + srow) * DMODEL + kc + sseg * 8];
    *(bfrag*)&Bs[srow * 40 + sseg * 8] =
        *(const bfrag*)&Wt[(n0 + srow) * DMODEL + kc + sseg * 8];
    __syncthreads();
    bfrag a = *(const bfrag*)&As[(wave * 16 + (lane & 15)) * 40 + (lane >> 4) * 8];
#pragma unroll
    for (int t = 0; t < 4; ++t) {
      bfrag b = *(const bfrag*)&Bs[(t * 16 + (lane & 15)) * 40 + (lane >> 4) * 8];
      acc[t] = __builtin_amdgcn_mfma_f32_16x16x32_bf16(a, b, acc[t], 0, 0, 0);
    }
    __syncthreads();
  }
  short* O = (which == 0) ? Qo : (which == 1) ? Ko : Vo;
#pragma unroll
  for (int t = 0; t < 4; ++t) {
    const int col = n0 + t * 16 + (lane & 15);
    const int h = col >> 6, d = col & 63;
#pragma unroll
    for (int r = 0; r < 4; ++r) {
      const int row = m0 + wave * 16 + (lane >> 4) * 4 + r;  // = b*SEQ + s
      const int b = row >> 11, s = row & 2047;
      O[((b * NHEAD + h) * SEQ + s) * HD + d] = f2bf(acc[t][r]);
    }
  }
}

// ---------------- output projection GEMM: bf16 in, FLOAT32 out ---------------
__global__ __launch_bounds__(256) void gemm_out(const short* __restrict__ X,
                                                const short* __restrict__ Wt,
                                                float* __restrict__ O) {
  __shared__ __align__(16) short As[64 * 40];
  __shared__ __align__(16) short Bs[64 * 40];
  const int m0 = blockIdx.y * 64, n0 = blockIdx.x * 64;
  const int tid = threadIdx.x, lane = tid & 63, wave = tid >> 6;
  const int srow = tid >> 2, sseg = tid & 3;
  f32x4 acc[4] = {};
  for (int kc = 0; kc < DMODEL; kc += 32) {
    *(bfrag*)&As[srow * 40 + sseg * 8] =
        *(const bfrag*)&X[(m0 + srow) * DMODEL + kc + sseg * 8];
    *(bfrag*)&Bs[srow * 40 + sseg * 8] =
        *(const bfrag*)&Wt[(n0 + srow) * DMODEL + kc + sseg * 8];
    __syncthreads();
    bfrag a = *(const bfrag*)&As[(wave * 16 + (lane & 15)) * 40 + (lane >> 4) * 8];
#pragma unroll
    for (int t = 0; t < 4; ++t) {
      bfrag b = *(const bfrag*)&Bs[(t * 16 + (lane & 15)) * 40 + (lane >> 4) * 8];
      acc[t] = __builtin_amdgcn_mfma_f32_16x16x32_bf16(a, b, acc[t], 0, 0, 0);
    }
    __syncthreads();
  }
#pragma unroll
  for (int t = 0; t < 4; ++t) {
    const int col = n0 + t * 16 + (lane & 15);
#pragma unroll
    for (int r = 0; r < 4; ++r) {
      const int row = m0 + wave * 16 + (lane >> 4) * 4 + r;
      O[(size_t)row * DMODEL + col] = acc[t][r];  // float32 store
    }
  }
}

// ---------------- flash attention (full key loop, -1e30 masking) -------------
// Q,K,V: (B,H,S,DH) bf16. ctx out: (B,S,D) bf16. grid: (S/64, B*H), block 256.
__global__ __launch_bounds__(256) void attn(const short* __restrict__ Q,
                                            const short* __restrict__ K,
                                            const short* __restrict__ V,
                                            const int* __restrict__ tmask,
                                            short* __restrict__ ctx) {
  __shared__ __align__(16) short Qs[64 * 72];
  __shared__ __align__(16) short Ks[64 * 72];
  __shared__ __align__(16) short Vts[64 * 72];  // Vt[d][k]
  __shared__ __align__(16) short Ps[4 * 16 * 72];
  __shared__ int tmq[64];
  __shared__ int tmk[64];
  const int bh = blockIdx.y;
  const int b = bh >> 3, h = bh & 7;
  const int q0 = blockIdx.x * 64;
  const int tid = threadIdx.x, lane = tid & 63, wave = tid >> 6;
  const size_t base = (size_t)bh * SEQ * HD;
  for (int i = tid; i < 64 * 8; i += 256) {
    const int r = i >> 3, sg = i & 7;
    *(bfrag*)&Qs[r * 72 + sg * 8] = *(const bfrag*)&Q[base + (size_t)(q0 + r) * HD + sg * 8];
  }
  if (tid < 64) tmq[tid] = tmask[b * SEQ + q0 + tid];

  f32x4 accO[4] = {};
  float mrow[4], lrow[4];
#pragma unroll
  for (int r = 0; r < 4; ++r) { mrow[r] = -1e30f; lrow[r] = 0.f; }
  const int qrow_loc = wave * 16 + (lane >> 4) * 4;  // + r

  for (int kc = 0; kc < SEQ; kc += 64) {
    __syncthreads();  // protect Ks/Vts (prev PV reads) before overwrite
    for (int i = tid; i < 64 * 8; i += 256) {
      const int kr = i >> 3, sg = i & 7;
      *(bfrag*)&Ks[kr * 72 + sg * 8] =
          *(const bfrag*)&K[base + (size_t)(kc + kr) * HD + sg * 8];
      bfrag v = *(const bfrag*)&V[base + (size_t)(kc + kr) * HD + sg * 8];
#pragma unroll
      for (int j = 0; j < 8; ++j) Vts[(sg * 8 + j) * 72 + kr] = v[j];
    }
    if (tid < 64) tmk[tid] = tmask[b * SEQ + kc + tid];
    __syncthreads();

    // S = Q @ K^T (this wave: 16 q-rows x 64 k-cols)
    f32x4 sacc[4] = {};
#pragma unroll
    for (int ds = 0; ds < 2; ++ds) {
      bfrag a = *(const bfrag*)&Qs[(wave * 16 + (lane & 15)) * 72 + ds * 32 + (lane >> 4) * 8];
#pragma unroll
      for (int t = 0; t < 4; ++t) {
        bfrag bb = *(const bfrag*)&Ks[(t * 16 + (lane & 15)) * 72 + ds * 32 + (lane >> 4) * 8];
        sacc[t] = __builtin_amdgcn_mfma_f32_16x16x32_bf16(a, bb, sacc[t], 0, 0, 0);
      }
    }

    // masked online softmax per row; write P (bf16) to per-wave LDS region
#pragma unroll
    for (int r = 0; r < 4; ++r) {
      const int qg = q0 + qrow_loc + r;
      const int tq = tmq[qrow_loc + r];
      float sv[4];
      float mx = -1e30f;
#pragma unroll
      for (int t = 0; t < 4; ++t) {
        const int kl = t * 16 + (lane & 15);
        const int kg = kc + kl;
        const bool ok = (kg <= qg) && (tmk[kl] != 0) && (tq != 0);
        sv[t] = ok ? sacc[t][r] * 0.125f : -1e30f;
        mx = fmaxf(mx, sv[t]);
      }
#pragma unroll
      for (int o = 1; o < 16; o <<= 1) mx = fmaxf(mx, __shfl_xor(mx, o));
      const float mnew = fmaxf(mrow[r], mx);
      float rsum = 0.f;
#pragma unroll
      for (int t = 0; t < 4; ++t) {
        const float p = __expf(sv[t] - mnew);
        rsum += p;
        Ps[wave * 1152 + ((lane >> 4) * 4 + r) * 72 + t * 16 + (lane & 15)] = f2bf(p);
      }
#pragma unroll
      for (int o = 1; o < 16; o <<= 1) rsum += __shfl_xor(rsum, o);
      const float alpha = __expf(mrow[r] - mnew);
      mrow[r] = mnew;
      lrow[r] = lrow[r] * alpha + rsum;
#pragma unroll
      for (int t = 0; t < 4; ++t) accO[t][r] *= alpha;
    }
    __syncthreads();  // P LDS write -> read

    // O += P @ V  (P: 16x64 in A-layout via LDS; V^T in Vts)
#pragma unroll
    for (int ks = 0; ks < 2; ++ks) {
      bfrag pa = *(const bfrag*)&Ps[wave * 1152 + (lane & 15) * 72 + ks * 32 + (lane >> 4) * 8];
#pragma unroll
      for (int t = 0; t < 4; ++t) {
        bfrag vb = *(const bfrag*)&Vts[(t * 16 + (lane & 15)) * 72 + ks * 32 + (lane >> 4) * 8];
        accO[t] = __builtin_amdgcn_mfma_f32_16x16x32_bf16(pa, vb, accO[t], 0, 0, 0);
      }
    }
  }

  // epilogue: ctx[b][q][h*64+d] = accO / l
#pragma unroll
  for (int t = 0; t < 4; ++t) {
    const int d = t * 16 + (lane & 15);
#pragma unroll
    for (int r = 0; r < 4; ++r) {
      const int qg = q0 + qrow_loc + r;
      const float val = accO[t][r] / lrow[r];
      ctx[((size_t)(b * SEQ + qg)) * DMODEL + h * HD + d] = f2bf(val);
    }
  }
}

extern "C" void kernel_launch(void* const* d_in, const int* in_sizes, int n_in,
                              void* d_out, int out_size, void* d_ws, size_t ws_size,
                              hipStream_t stream) {
  const void* X = d_in[0];
  const int* tmask = (const int*)d_in[1];
  const void* Wq = d_in[2];
  const void* Wk = d_in[3];
  const void* Wv = d_in[4];
  const void* Wo = d_in[5];
  float* out = (float*)d_out;  // reference returns float32
  char* ws = (char*)d_ws;

  const size_t WELEM = (size_t)DMODEL * DMODEL;           // 262144
  const size_t TELEM = (size_t)BATCH * NHEAD * SEQ * HD;  // 4,194,304

  int* flag = (int*)ws;                       // [0, 4 KB)
  short* wt = (short*)(ws + 4096);            // 2 MB: 4 transposed bf16 weights
  short* Xb = (short*)(ws + 4096 + 2097152);  // 8 MB each below
  short* Qb = Xb + TELEM;
  short* Kb = Qb + TELEM;
  short* Vb = Kb + TELEM;
  short* Cb = Vb + TELEM;

  sniff<<<1, 64, 0, stream>>>((const uint32_t*)X, flag);
  conv_x<<<(int)(TELEM / (256 * 8)), 256, 0, stream>>>(X, Xb, flag);
  dim3 tb(32, 8);
  transpose_w<<<dim3(16, 16), tb, 0, stream>>>(Wq, wt, flag);
  transpose_w<<<dim3(16, 16), tb, 0, stream>>>(Wk, wt + WELEM, flag);
  transpose_w<<<dim3(16, 16), tb, 0, stream>>>(Wv, wt + 2 * WELEM, flag);
  transpose_w<<<dim3(16, 16), tb, 0, stream>>>(Wo, wt + 3 * WELEM, flag);
  gemm_qkv<<<dim3(8, 128, 3), 256, 0, stream>>>(Xb, wt, Qb, Kb, Vb);
  attn<<<dim3(SEQ / 64, BATCH * NHEAD), 256, 0, stream>>>(Qb, Kb, Vb, tmask, Cb);
  gemm_out<<<dim3(8, 128), 256, 0, stream>>>(Cb, wt + 3 * WELEM, out);
}